// Round 10
// baseline (3520.872 us; speedup 1.0000x reference)
//
#include <hip/hip_runtime.h>
#include <math.h>

// Problem constants
#define DD   256
#define TTT  512
#define JJJ  128
#define BBB  32
#define NC   1536     // 6*D combined gate columns (fwd 0..767, bwd 768..1535)
#define ROWS_ALL 36864

typedef _Float16 v2h __attribute__((ext_vector_type(2)));
typedef _Float16 v4h __attribute__((ext_vector_type(4)));
typedef _Float16 v8h __attribute__((ext_vector_type(8)));
typedef short short8 __attribute__((ext_vector_type(8)));
typedef float f32x4 __attribute__((ext_vector_type(4)));

__device__ __forceinline__ short f2bf(float f) {
    unsigned u = __float_as_uint(f);
    unsigned r = (u + 0x7FFFu + ((u >> 16) & 1u)) >> 16;   // RNE
    return (short)r;
}

// ---------------------------------------------------------------------------
// K0: prep — token table, wh16 (fp16 c-major whh concat), biases, Bt bf16, w2h
// ---------------------------------------------------------------------------
__global__ __launch_bounds__(256) void prep_kernel(
    const int* __restrict__ cmnt, const int* __restrict__ src_tok, const int* __restrict__ tgt_tok,
    const float* __restrict__ wih_f, const float* __restrict__ wih_b,
    const float* __restrict__ whh_f, const float* __restrict__ whh_b,
    const float* __restrict__ bih_f, const float* __restrict__ bih_b,
    const float* __restrict__ bhh_f, const float* __restrict__ bhh_b,
    const float* __restrict__ w2,
    int* __restrict__ tok_all, _Float16* __restrict__ wh16,
    float* __restrict__ bihc, float* __restrict__ bhhc, short* __restrict__ Bt,
    _Float16* __restrict__ w2h)
{
    const int idx = blockIdx.x * blockDim.x + threadIdx.x;
    const int stride = gridDim.x * blockDim.x;
    for (int i = idx; i < ROWS_ALL; i += stride)
        tok_all[i] = (i < 16384) ? src_tok[i] : (i < 32768) ? tgt_tok[i - 16384] : cmnt[i - 32768];
    for (int i = idx; i < 393216; i += stride)
        wh16[i] = (_Float16)(i < 196608 ? whh_f[i] : whh_b[i - 196608]);
    for (int i = idx; i < 393216; i += stride)
        Bt[i] = f2bf(i < 196608 ? wih_f[i] : wih_b[i - 196608]);
    for (int i = idx; i < NC; i += stride) {
        bihc[i] = (i < 768) ? bih_f[i] : bih_b[i - 768];
        bhhc[i] = (i < 768) ? bhh_f[i] : bhh_b[i - 768];
    }
    for (int i = idx; i < 512; i += stride)
        w2h[i] = (_Float16)w2[i];
}

// K0b: gather token embedding rows to bf16 A matrix (nrows x 256)
__global__ __launch_bounds__(256) void gatherA_kernel(
    const int* __restrict__ tok, int nrows,
    const float* __restrict__ emb, short* __restrict__ A)
{
    const int idx = blockIdx.x * blockDim.x + threadIdx.x;
    const int stride = gridDim.x * blockDim.x;
    const int ngroups = nrows * 64;
    for (int g = idx; g < ngroups; g += stride) {
        const int i = g >> 6;
        const int kq = (g & 63) << 2;
        const float4 v = *(const float4*)(emb + (size_t)tok[i] * 256 + kq);
        short4 s;
        s.x = f2bf(v.x); s.y = f2bf(v.y); s.z = f2bf(v.z); s.w = f2bf(v.w);
        *(short4*)(A + (size_t)i * 256 + kq) = s;
    }
}

// ---------------------------------------------------------------------------
// K1: gi GEMM via bf16 MFMA 16x16x32, LDS-staged; standard fp16 gi output
// (row*NC + col). bhh_r / bhh_z folded into bias here; bhh_n stays in gru.
// ---------------------------------------------------------------------------
#define LP 40   // padded LDS row pitch in 2-byte units
__global__ __launch_bounds__(256) void gi_mfma(
    const short* __restrict__ A, const short* __restrict__ Bt,
    const float* __restrict__ bihc, const float* __restrict__ bhhc,
    _Float16* __restrict__ gi)
{
    __shared__ __align__(16) short As[128 * LP];
    __shared__ __align__(16) short Bs[128 * LP];
    const int tid = threadIdx.x;
    const int wave = tid >> 6, lane = tid & 63;
    const int quad = lane >> 4, l16 = lane & 15;
    const int m0 = blockIdx.x * 128, n0 = blockIdx.y * 128;
    const int wm = (wave & 1) * 64, wn = (wave >> 1) * 64;

    const int sr = tid >> 2;
    const int sk = (tid & 3) * 8;
    const short* ga0 = A  + (size_t)(m0 + sr) * 256 + sk;
    const short* ga1 = A  + (size_t)(m0 + sr + 64) * 256 + sk;
    const short* gb0 = Bt + (size_t)(n0 + sr) * 256 + sk;
    const short* gb1 = Bt + (size_t)(n0 + sr + 64) * 256 + sk;

    f32x4 acc[4][4];
    #pragma unroll
    for (int i = 0; i < 4; ++i)
        #pragma unroll
        for (int j = 0; j < 4; ++j) acc[i][j] = (f32x4){0.f, 0.f, 0.f, 0.f};

    for (int k0 = 0; k0 < 256; k0 += 32) {
        const short8 a0 = *(const short8*)(ga0 + k0);
        const short8 a1 = *(const short8*)(ga1 + k0);
        const short8 b0 = *(const short8*)(gb0 + k0);
        const short8 b1 = *(const short8*)(gb1 + k0);
        __syncthreads();
        *(short8*)&As[sr * LP + sk] = a0;
        *(short8*)&As[(sr + 64) * LP + sk] = a1;
        *(short8*)&Bs[sr * LP + sk] = b0;
        *(short8*)&Bs[(sr + 64) * LP + sk] = b1;
        __syncthreads();
        short8 af[4], bf[4];
        #pragma unroll
        for (int i = 0; i < 4; ++i)
            af[i] = *(const short8*)&As[(wm + i * 16 + l16) * LP + quad * 8];
        #pragma unroll
        for (int j = 0; j < 4; ++j)
            bf[j] = *(const short8*)&Bs[(wn + j * 16 + l16) * LP + quad * 8];
        #pragma unroll
        for (int i = 0; i < 4; ++i)
            #pragma unroll
            for (int j = 0; j < 4; ++j)
                acc[i][j] = __builtin_amdgcn_mfma_f32_16x16x32_bf16(af[i], bf[j], acc[i][j], 0, 0, 0);
    }

    #pragma unroll
    for (int j = 0; j < 4; ++j) {
        const int col = n0 + wn + j * 16 + l16;
        const int g = (col - ((col >= 768) ? 768 : 0)) >> 8;
        const float bias = bihc[col] + ((g < 2) ? bhhc[col] : 0.f);
        #pragma unroll
        for (int i = 0; i < 4; ++i) {
            const int r0 = m0 + wm + i * 16 + quad * 4;
            #pragma unroll
            for (int reg = 0; reg < 4; ++reg)
                gi[(size_t)(r0 + reg) * NC + col] = (_Float16)(acc[i][j][reg] + bias);
        }
    }
}

// ---------------------------------------------------------------------------
// K2: GRU recurrence via f16 MFMA across batch.
// 12 blocks = (chain 0..5) x (bhalf); 512 thr = 8 waves (2/SIMD, 256 reg cap).
// Weight placement respects the unified-file budget:
//   r,z gates: 128 regs/lane (2 gates x 2 u-tiles x 8 ks x v8h) — resident.
//   n gate:    LDS (256 rows x pitch 260 fp16 = 133 KB; CDNA4 has 160 KB).
// hbuf pitch 260 halfs (130 dw = 2 mod 32 -> 2-way = free). Per step:
// 24 ds_read_b128 (h + n-frags) + 48 MFMA + in-register gates.
// Raw barrier (lgkmcnt-only) — NO vmcnt(0) drain: gi loads / e stores
// retire asynchronously across steps.
// ---------------------------------------------------------------------------
#define HP 260
__global__ __launch_bounds__(512, 2) void gru_kernel(
    const _Float16* __restrict__ gi, const _Float16* __restrict__ wh16,
    const float* __restrict__ bhhc,
    _Float16* __restrict__ e_src, _Float16* __restrict__ e_tgt, _Float16* __restrict__ e_cmnt)
{
    const int chain = (int)(blockIdx.x >> 1);
    const int bhalf = (int)(blockIdx.x & 1);
    const int seq = chain >> 1, dir = chain & 1;
    const int Tlen = (seq == 2) ? JJJ : TTT;
    const int seqbase = (seq == 0) ? 0 : (seq == 1) ? 16384 : 32768;
    _Float16* e = (seq == 0) ? e_src : (seq == 1) ? e_tgt : e_cmnt;
    const int cb = dir * 768;

    const int tid = threadIdx.x;
    const int w = tid >> 6, lane = tid & 63;
    const int quad = lane >> 4, l16 = lane & 15;
    const int j0 = w * 32;

    __shared__ __align__(16) _Float16 wnlds[256 * HP];     // n-gate weights, 133 KB
    __shared__ __align__(16) _Float16 hbuf[2][16 * HP];    // 16.6 KB

    // Cooperative n-gate weight load into LDS (once).
    for (int idx = tid; idx < 256 * 32; idx += 512) {
        const int row = idx >> 5, ch = idx & 31;
        *(v8h*)&wnlds[row * HP + ch * 8] =
            *(const v8h*)(wh16 + (size_t)(cb + 512 + row) * 256 + ch * 8);
    }
    // r,z weights resident: Wrz[g][u][ks] covers n = cb+g*256+j0+u*16+l16,
    // k = ks*32 + quad*8 .. +7.
    v8h Wrz[2][2][8];
    #pragma unroll
    for (int g = 0; g < 2; ++g)
        #pragma unroll
        for (int u = 0; u < 2; ++u) {
            const _Float16* wrow = wh16 + (size_t)(cb + g * 256 + j0 + u * 16 + l16) * 256 + quad * 8;
            #pragma unroll
            for (int ks = 0; ks < 8; ++ks)
                Wrz[g][u][ks] = *(const v8h*)(wrow + ks * 32);
        }

    float bhn[2];
    #pragma unroll
    for (int u = 0; u < 2; ++u) bhn[u] = bhhc[cb + 512 + j0 + u * 16 + l16];

    float hp[2][4];
    #pragma unroll
    for (int u = 0; u < 2; ++u)
        #pragma unroll
        for (int reg = 0; reg < 4; ++reg) hp[u][reg] = 0.f;

    for (int i = tid; i < 16 * HP; i += 512) hbuf[0][i] = (_Float16)0.f;
    __syncthreads();

    const int t0 = dir ? (Tlen - 1) : 0;
    const long tstep = dir ? -1L : 1L;
    // gi lane base: row = seqbase + (bhalf*16 + quad*4 + reg)*Tlen + t; col = cb + g*256 + j0 + u*16 + l16
    const _Float16* gbase = gi
        + ((size_t)(seqbase + (bhalf * 16 + quad * 4) * Tlen + t0)) * NC + cb + j0 + l16;
    const long gistep = tstep * NC;
    const long gregstride = (long)Tlen * NC;

    _Float16* ecur = e + ((size_t)(bhalf * 16 + quad * 4) * Tlen + t0) * 512 + dir * 256 + j0 + l16;
    const long estep = tstep * 512;
    const long eregstride = (long)Tlen * 512;

    for (int s = 0; s < Tlen; ++s) {
        // gi loads (24 x b16) issued at step top, consumed in the gate phase
        _Float16 gv[3][2][4];
        #pragma unroll
        for (int g = 0; g < 3; ++g)
            #pragma unroll
            for (int u = 0; u < 2; ++u)
                #pragma unroll
                for (int reg = 0; reg < 4; ++reg)
                    gv[g][u][reg] = gbase[(long)reg * gregstride + g * 256 + u * 16];

        f32x4 acc[3][2];
        #pragma unroll
        for (int g = 0; g < 3; ++g)
            #pragma unroll
            for (int u = 0; u < 2; ++u) acc[g][u] = (f32x4){0.f, 0.f, 0.f, 0.f};

        const _Float16* hb = &hbuf[s & 1][l16 * HP + quad * 8];
        const _Float16* wn0 = &wnlds[(j0 + l16) * HP + quad * 8];
        const _Float16* wn1 = &wnlds[(j0 + 16 + l16) * HP + quad * 8];
        #pragma unroll
        for (int ks = 0; ks < 8; ++ks) {
            const v8h Af = *(const v8h*)(hb + ks * 32);
            const v8h Bn0 = *(const v8h*)(wn0 + ks * 32);
            const v8h Bn1 = *(const v8h*)(wn1 + ks * 32);
            acc[0][0] = __builtin_amdgcn_mfma_f32_16x16x32_f16(Af, Wrz[0][0][ks], acc[0][0], 0, 0, 0);
            acc[0][1] = __builtin_amdgcn_mfma_f32_16x16x32_f16(Af, Wrz[0][1][ks], acc[0][1], 0, 0, 0);
            acc[1][0] = __builtin_amdgcn_mfma_f32_16x16x32_f16(Af, Wrz[1][0][ks], acc[1][0], 0, 0, 0);
            acc[1][1] = __builtin_amdgcn_mfma_f32_16x16x32_f16(Af, Wrz[1][1][ks], acc[1][1], 0, 0, 0);
            acc[2][0] = __builtin_amdgcn_mfma_f32_16x16x32_f16(Af, Bn0, acc[2][0], 0, 0, 0);
            acc[2][1] = __builtin_amdgcn_mfma_f32_16x16x32_f16(Af, Bn1, acc[2][1], 0, 0, 0);
        }

        // gates in-register; C-layout: col=l16 (j), row=quad*4+reg (b)
        _Float16* hw = &hbuf[(s + 1) & 1][(quad * 4) * HP + j0 + l16];
        #pragma unroll
        for (int u = 0; u < 2; ++u) {
            #pragma unroll
            for (int reg = 0; reg < 4; ++reg) {
                const float gr = acc[0][u][reg] + (float)gv[0][u][reg];
                const float gz = acc[1][u][reg] + (float)gv[1][u][reg];
                const float r = 1.f / (1.f + __expf(-gr));
                const float z = 1.f / (1.f + __expf(-gz));
                const float x = (float)gv[2][u][reg] + r * (acc[2][u][reg] + bhn[u]);
                const float ex = __expf(2.f * x);
                const float n = 1.f - 2.f / (ex + 1.f);        // tanh(x)
                const float hnew = (1.f - z) * n + z * hp[u][reg];
                hp[u][reg] = hnew;
                ecur[(long)reg * eregstride + u * 16] = (_Float16)hnew;   // async store
                hw[reg * HP + u * 16] = (_Float16)hnew;
            }
        }
        gbase += gistep;
        ecur += estep;
        // LDS-visibility-only barrier: no vmcnt(0) drain of gi loads / e stores
        asm volatile("s_waitcnt lgkmcnt(0)\n\ts_barrier" ::: "memory");
    }
}

// ---------------------------------------------------------------------------
// K3: sim via f16 MFMA 16x16x32.  S[b,t,j] = sum_d (ctx*w2)[t,d]*ec[j,d] + act
// ---------------------------------------------------------------------------
__global__ __launch_bounds__(256) void sim_mfma(
    const _Float16* __restrict__ e_src, const _Float16* __restrict__ e_tgt,
    const _Float16* __restrict__ e_cmnt, const _Float16* __restrict__ w2h,
    const float* __restrict__ w2,
    const int* __restrict__ src_action, const int* __restrict__ tgt_action,
    float* __restrict__ S, float* __restrict__ rowmaxP)
{
    const int sb = (int)blockIdx.z;
    const int seq = sb >> 5, b = sb & 31;
    const int t0 = blockIdx.x * 128;
    const _Float16* ctx = ((seq == 0) ? e_src : e_tgt) + (size_t)b * 512 * 512;
    const _Float16* ec = e_cmnt + (size_t)b * 128 * 512;
    const int* act = (seq == 0) ? src_action : tgt_action;

    __shared__ __align__(16) _Float16 As[128 * LP];
    __shared__ __align__(16) _Float16 Bs[128 * LP];
    const int tid = threadIdx.x;
    const int wave = tid >> 6, lane = tid & 63;
    const int quad = lane >> 4, l16 = lane & 15;
    const int wm = (wave & 1) * 64, wn = (wave >> 1) * 64;
    const int sr = tid >> 2;
    const int sk = (tid & 3) * 8;

    const _Float16* ga0 = ctx + (size_t)(t0 + sr) * 512 + sk;
    const _Float16* ga1 = ctx + (size_t)(t0 + sr + 64) * 512 + sk;
    const _Float16* gb0 = ec + (size_t)sr * 512 + sk;
    const _Float16* gb1 = ec + (size_t)(sr + 64) * 512 + sk;

    f32x4 acc[4][4];
    #pragma unroll
    for (int i = 0; i < 4; ++i)
        #pragma unroll
        for (int j = 0; j < 4; ++j) acc[i][j] = (f32x4){0.f, 0.f, 0.f, 0.f};

    for (int k0 = 0; k0 < 512; k0 += 32) {
        v8h a0 = *(const v8h*)(ga0 + k0);
        v8h a1 = *(const v8h*)(ga1 + k0);
        const v8h b0 = *(const v8h*)(gb0 + k0);
        const v8h b1 = *(const v8h*)(gb1 + k0);
        const v8h w8 = *(const v8h*)(w2h + k0 + sk);
        a0 = a0 * w8;
        a1 = a1 * w8;
        __syncthreads();
        *(v8h*)&As[sr * LP + sk] = a0;
        *(v8h*)&As[(sr + 64) * LP + sk] = a1;
        *(v8h*)&Bs[sr * LP + sk] = b0;
        *(v8h*)&Bs[(sr + 64) * LP + sk] = b1;
        __syncthreads();
        v8h af[4], bf[4];
        #pragma unroll
        for (int i = 0; i < 4; ++i)
            af[i] = *(const v8h*)&As[(wm + i * 16 + l16) * LP + quad * 8];
        #pragma unroll
        for (int j = 0; j < 4; ++j)
            bf[j] = *(const v8h*)&Bs[(wn + j * 16 + l16) * LP + quad * 8];
        #pragma unroll
        for (int i = 0; i < 4; ++i)
            #pragma unroll
            for (int j = 0; j < 4; ++j)
                acc[i][j] = __builtin_amdgcn_mfma_f32_16x16x32_f16(af[i], bf[j], acc[i][j], 0, 0, 0);
    }

    const float w2a = w2[512];
    #pragma unroll
    for (int i = 0; i < 4; ++i) {
        #pragma unroll
        for (int reg = 0; reg < 4; ++reg) {
            const int t = t0 + wm + i * 16 + quad * 4 + reg;
            const float aterm = (float)act[b * 512 + t] * w2a;
            float m = -1e30f;
            #pragma unroll
            for (int j = 0; j < 4; ++j) {
                const float v = acc[i][j][reg] + aterm;
                S[((size_t)(sb * 512 + t)) * 128 + wn + j * 16 + l16] = v;
                m = fmaxf(m, v);
            }
            m = fmaxf(m, __shfl_xor(m, 1));
            m = fmaxf(m, __shfl_xor(m, 2));
            m = fmaxf(m, __shfl_xor(m, 4));
            m = fmaxf(m, __shfl_xor(m, 8));
            if (l16 == 0)
                rowmaxP[(size_t)(wave >> 1) * 32768 + sb * 512 + t] = m;
        }
    }
}

// K5: softmax over t (512) per (seq,b)
__global__ __launch_bounds__(256) void softmax_kernel(const float* __restrict__ rowmaxP, float* __restrict__ bw)
{
    const int base = blockIdx.x * 512;
    const int tid = threadIdx.x;
    __shared__ float red[256];
    const float v0 = fmaxf(rowmaxP[base + tid], rowmaxP[32768 + base + tid]);
    const float v1 = fmaxf(rowmaxP[base + 256 + tid], rowmaxP[32768 + base + 256 + tid]);
    red[tid] = fmaxf(v0, v1);
    __syncthreads();
    for (int off = 128; off > 0; off >>= 1) {
        if (tid < off) red[tid] = fmaxf(red[tid], red[tid + off]);
        __syncthreads();
    }
    const float M = red[0];
    __syncthreads();
    const float e0 = __expf(v0 - M), e1 = __expf(v1 - M);
    red[tid] = e0 + e1;
    __syncthreads();
    for (int off = 128; off > 0; off >>= 1) {
        if (tid < off) red[tid] += red[tid + off];
        __syncthreads();
    }
    const float inv = 1.f / red[0];
    bw[base + tid] = e0 * inv;
    bw[base + 256 + tid] = e1 * inv;
}

// K6: outSP[c][sb*128+j] = sum_{t in chunk c} bw[sb,t] * S[sb,t,j]
__global__ __launch_bounds__(256) void weighted_kernel(
    const float* __restrict__ S, const float* __restrict__ bw, float* __restrict__ outSP)
{
    const int sb = blockIdx.x;
    const int ch = blockIdx.y;
    const int tid = threadIdx.x;
    const int j = tid & 127, half = tid >> 7;
    const float* Sb = S + (size_t)sb * 512 * 128;
    const float* w = bw + sb * 512;
    const int tb = ch * 64 + half * 32;
    float acc = 0.f;
    for (int t = tb; t < tb + 32; ++t)
        acc = fmaf(w[t], Sb[(size_t)t * 128 + j], acc);
    __shared__ float red[256];
    red[tid] = acc;
    __syncthreads();
    if (half == 0) outSP[(size_t)ch * 8192 + sb * 128 + j] = red[j] + red[128 + j];
}

// K7: sum chunk partials; write S_diff and result into d_out
__global__ __launch_bounds__(256) void final_kernel(
    const float* __restrict__ outSP, const float* __restrict__ rank_w,
    const float* __restrict__ rank_b, float* __restrict__ out)
{
    __shared__ float sArr[8192];
    const int tid = threadIdx.x;
    for (int q = tid; q < 8192; q += 256) {
        float s = 0.f;
        #pragma unroll
        for (int c = 0; c < 8; ++c) s += outSP[(size_t)c * 8192 + q];
        sArr[q] = s;
    }
    __syncthreads();
    for (int q = tid; q < 8192; q += 256) {
        const int b = q >> 8, c = q & 255;
        out[32 + q] = (c < 128) ? sArr[b * 128 + c] : sArr[4096 + b * 128 + (c - 128)];
    }
    if (tid < 32) {
        float acc = rank_b[0];
        for (int c = 0; c < 128; ++c) acc = fmaf(sArr[tid * 128 + c], rank_w[c], acc);
        for (int c = 0; c < 128; ++c) acc = fmaf(sArr[4096 + tid * 128 + c], rank_w[128 + c], acc);
        out[tid] = acc;
    }
}

// ---------------------------------------------------------------------------
extern "C" void kernel_launch(void* const* d_in, const int* in_sizes, int n_in,
                              void* d_out, int out_size, void* d_ws, size_t ws_size,
                              hipStream_t stream)
{
    const int* cmnt       = (const int*)d_in[0];
    const int* src_token  = (const int*)d_in[1];
    const int* tgt_token  = (const int*)d_in[2];
    const int* src_action = (const int*)d_in[3];
    const int* tgt_action = (const int*)d_in[4];
    const float* emb    = (const float*)d_in[5];
    const float* wih_f  = (const float*)d_in[6];
    const float* whh_f  = (const float*)d_in[7];
    const float* bih_f  = (const float*)d_in[8];
    const float* bhh_f  = (const float*)d_in[9];
    const float* wih_b  = (const float*)d_in[10];
    const float* whh_b  = (const float*)d_in[11];
    const float* bih_b  = (const float*)d_in[12];
    const float* bhh_b  = (const float*)d_in[13];
    const float* w2     = (const float*)d_in[14];
    const float* rank_w = (const float*)d_in[15];
    const float* rank_b = (const float*)d_in[16];
    float* out = (float*)d_out;

    // Workspace layout (fp32 slots). e_* and gi are fp16. Tier-A fit proven R6+.
    float* ws = (float*)d_ws;
    size_t off = 0;
    int*   tok_all = (int*)(ws + off); off += 36864;
    short* Bt_bf16 = (short*)(ws + off); off += 196608;        // 1536x256 bf16
    _Float16* wh16 = (_Float16*)(ws + off); off += 196608;     // 1536x256 fp16
    float* bihc   = ws + off; off += 1536;
    float* bhhc   = ws + off; off += 1536;
    _Float16* w2h = (_Float16*)(ws + off); off += 256;
    float* rowmaxP = ws + off; off += 65536;
    float* bw     = ws + off; off += 32768;
    float* outSP  = ws + off; off += 65536;
    _Float16* e_src  = (_Float16*)(ws + off); off += 4194304;
    _Float16* e_tgt  = (_Float16*)(ws + off); off += 4194304;
    _Float16* e_cmnt = (_Float16*)(ws + off); off += 1048576;
    float* S      = ws + off; off += 4194304;
    _Float16* gih = (_Float16*)(ws + off);                     // 36864x1536 fp16

    hipLaunchKernelGGL(prep_kernel, dim3(512), dim3(256), 0, stream,
        cmnt, src_token, tgt_token, wih_f, wih_b, whh_f, whh_b,
        bih_f, bih_b, bhh_f, bhh_b, w2, tok_all, wh16, bihc, bhhc, Bt_bf16, w2h);

    // A_bf16 aliases e_src+e_tgt, consumed before gru writes e.
    short* A = (short*)e_src;
    hipLaunchKernelGGL(gatherA_kernel, dim3(4096), dim3(256), 0, stream,
        tok_all, 36864, emb, A);
    hipLaunchKernelGGL(gi_mfma, dim3(288, 12), dim3(256), 0, stream,
        A, Bt_bf16, bihc, bhhc, gih);
    hipLaunchKernelGGL(gru_kernel, dim3(12), dim3(512), 0, stream,
        gih, wh16, bhhc, e_src, e_tgt, e_cmnt);

    hipLaunchKernelGGL(sim_mfma, dim3(4, 1, 64), dim3(256), 0, stream,
        e_src, e_tgt, e_cmnt, w2h, w2, src_action, tgt_action, S, rowmaxP);
    hipLaunchKernelGGL(softmax_kernel, dim3(64), dim3(256), 0, stream, rowmaxP, bw);
    hipLaunchKernelGGL(weighted_kernel, dim3(64, 8), dim3(256), 0, stream, S, bw, outSP);
    hipLaunchKernelGGL(final_kernel, dim3(1), dim3(256), 0, stream, outSP, rank_w, rank_b, out);
}